// Round 1
// baseline (30.042 us; speedup 1.0000x reference)
//
#include <hip/hip_runtime.h>
#include <hip/hip_bf16.h>
#include <math.h>

// Problem: B=8, N=20, H=W=512. loss = sum(bce*valid)/cnt over pixels where
// the last point (max n) with exp(-d2/(2*sigma^2)) > 0.1 defines the label.
// Radius^2 threshold: -2*sigma^2*ln(0.1) = 50*ln(10).

#define R2_THRESH 115.12925464970229f
#define HW 512
#define NPTS 20
#define ROWS_PER_BLOCK 8
#define NBLOCKS (8 * (HW / ROWS_PER_BLOCK))   // 8 batches * 64 chunks = 512

__global__ __launch_bounds__(256)
void pce_main_kernel(const float* __restrict__ y_pred,
                     const int* __restrict__ point_labels,
                     const float* __restrict__ point_coords,
                     float* __restrict__ ws) {
    const int b     = blockIdx.x >> 6;        // 64 chunks per batch
    const int chunk = blockIdx.x & 63;
    const int y0    = chunk * ROWS_PER_BLOCK;
    const int tid   = threadIdx.x;

    __shared__ float p_yc[NPTS], p_xc[NPTS], p_lab[NPTS];
    __shared__ float s_xc[NPTS], s_lim[NPTS], s_lab[NPTS];
    __shared__ int   s_nact;

    if (tid < NPTS) {
        p_yc[tid]  = point_coords[b * (NPTS * 2) + tid * 2 + 0] * (float)HW;
        p_xc[tid]  = point_coords[b * (NPTS * 2) + tid * 2 + 1] * (float)HW;
        p_lab[tid] = (float)point_labels[b * NPTS + tid];
    }

    float sum = 0.0f;
    float cnt = 0.0f;
    const float* ybase = y_pred + (size_t)b * HW * HW;

    for (int r = 0; r < ROWS_PER_BLOCK; ++r) {
        const int y = y0 + r;
        __syncthreads();   // r=0: p_* visible; r>0: protect s_* overwrite
        if (tid == 0) {
            int c = 0;
            const float fy = (float)y;
            for (int n = 0; n < NPTS; ++n) {
                float dy  = fy - p_yc[n];
                float lim = R2_THRESH - dy * dy;
                if (lim > 0.0f) {        // point active on this row
                    s_xc[c]  = p_xc[n];  // keep increasing-n order -> last hit wins
                    s_lim[c] = lim;
                    s_lab[c] = p_lab[n];
                    ++c;
                }
            }
            s_nact = c;
        }
        __syncthreads();
        const int na = s_nact;
        if (na > 0) {
            for (int px = tid; px < HW; px += 256) {
                const float fx = (float)px;
                float lab = 0.0f;
                bool  valid = false;
                for (int k = 0; k < na; ++k) {
                    float dx = fx - s_xc[k];
                    if (dx * dx < s_lim[k]) { lab = s_lab[k]; valid = true; }
                }
                if (valid) {
                    float l   = ybase[y * HW + px];
                    float bce = fmaxf(l, 0.0f) - l * lab + log1pf(expf(-fabsf(l)));
                    sum += bce;
                    cnt += 1.0f;
                }
            }
        }
    }

    // deterministic block reduction: wave (64-lane) shuffle, then LDS across 4 waves
    for (int off = 32; off > 0; off >>= 1) {
        sum += __shfl_down(sum, off, 64);
        cnt += __shfl_down(cnt, off, 64);
    }
    __shared__ float rs[4], rc[4];
    __syncthreads();                 // s_* no longer needed; rs/rc fresh
    if ((tid & 63) == 0) { rs[tid >> 6] = sum; rc[tid >> 6] = cnt; }
    __syncthreads();
    if (tid == 0) {
        float S = 0.0f, C = 0.0f;
        #pragma unroll
        for (int i = 0; i < 4; ++i) { S += rs[i]; C += rc[i]; }
        ws[blockIdx.x * 2 + 0] = S;
        ws[blockIdx.x * 2 + 1] = C;
    }
}

__global__ __launch_bounds__(256)
void pce_final_kernel(const float* __restrict__ ws, float* __restrict__ out) {
    __shared__ float rs[256], rc[256];
    const int tid = threadIdx.x;
    float S = 0.0f, C = 0.0f;
    for (int i = tid; i < NBLOCKS; i += 256) {
        S += ws[2 * i + 0];
        C += ws[2 * i + 1];
    }
    rs[tid] = S; rc[tid] = C;
    __syncthreads();
    for (int off = 128; off > 0; off >>= 1) {
        if (tid < off) { rs[tid] += rs[tid + off]; rc[tid] += rc[tid + off]; }
        __syncthreads();
    }
    if (tid == 0) {
        float c = rc[0];
        out[0] = (c > 0.0f) ? (rs[0] / c) : 0.0f;   // c>=1 when c>0, so /c == /max(c,1)
    }
}

extern "C" void kernel_launch(void* const* d_in, const int* in_sizes, int n_in,
                              void* d_out, int out_size, void* d_ws, size_t ws_size,
                              hipStream_t stream) {
    const float* y_pred       = (const float*)d_in[0];   // (8,1,512,512) f32
    const int*   point_labels = (const int*)d_in[1];     // (8,20) i32
    const float* point_coords = (const float*)d_in[2];   // (8,20,2) f32
    float*       out          = (float*)d_out;           // scalar f32
    float*       ws           = (float*)d_ws;            // 512*2 floats, fully overwritten

    pce_main_kernel<<<NBLOCKS, 256, 0, stream>>>(y_pred, point_labels, point_coords, ws);
    pce_final_kernel<<<1, 256, 0, stream>>>(ws, out);
}

// Round 2
// 22.251 us; speedup vs baseline: 1.3501x; 1.3501x over previous
//
#include <hip/hip_runtime.h>
#include <hip/hip_bf16.h>
#include <math.h>

// B=8, N=20, H=W=512. loss = sum(bce*valid)/cnt where the last point n with
// exp(-d2/(2*5^2)) > 0.1 (<=> d2 < 50*ln10) defines the per-pixel label.

#define R2_THRESH 115.12925464970229f
#define HW 512
#define NPTS 20
#define ROWS_PER_BLOCK 8
#define NBLOCKS (8 * (HW / ROWS_PER_BLOCK))   // 512 blocks = 2 per CU

__global__ __launch_bounds__(256)
void pce_main_kernel(const float* __restrict__ y_pred,
                     const int* __restrict__ point_labels,
                     const float* __restrict__ point_coords,
                     float* __restrict__ ws) {
    const int b     = blockIdx.x >> 6;        // 64 row-chunks per batch
    const int chunk = blockIdx.x & 63;
    const int y0    = chunk * ROWS_PER_BLOCK;
    const int tid   = threadIdx.x;

    __shared__ float p_yc[NPTS], p_xc[NPTS], p_lab[NPTS];
    __shared__ float s_xc[ROWS_PER_BLOCK][NPTS];
    __shared__ float s_lim[ROWS_PER_BLOCK][NPTS];
    __shared__ float s_lab[ROWS_PER_BLOCK][NPTS];
    __shared__ int   s_na[ROWS_PER_BLOCK];
    __shared__ int   s_xlo[ROWS_PER_BLOCK], s_xhi[ROWS_PER_BLOCK];

    if (tid < NPTS) {
        p_yc[tid]  = point_coords[b * (NPTS * 2) + tid * 2 + 0] * (float)HW;
        p_xc[tid]  = point_coords[b * (NPTS * 2) + tid * 2 + 1] * (float)HW;
        p_lab[tid] = (float)point_labels[b * NPTS + tid];
    }
    __syncthreads();

    // one thread per row: compact active points (order preserved -> last wins)
    if (tid < ROWS_PER_BLOCK) {
        const float fy = (float)(y0 + tid);
        int c = 0;
        float xlo = 1e9f, xhi = -1e9f;
        for (int n = 0; n < NPTS; ++n) {
            float dy  = fy - p_yc[n];
            float lim = R2_THRESH - dy * dy;
            if (lim > 0.0f) {
                s_xc[tid][c]  = p_xc[n];
                s_lim[tid][c] = lim;
                s_lab[tid][c] = p_lab[n];
                ++c;
                float s = sqrtf(lim);
                xlo = fminf(xlo, p_xc[n] - s);
                xhi = fmaxf(xhi, p_xc[n] + s);
            }
        }
        s_na[tid]  = c;
        s_xlo[tid] = max(0, (int)floorf(xlo));
        s_xhi[tid] = min(HW - 1, (int)ceilf(xhi));
    }
    __syncthreads();

    float sum = 0.0f;
    float cnt = 0.0f;
    const float* ybase = y_pred + (size_t)b * HW * HW;

    for (int r = 0; r < ROWS_PER_BLOCK; ++r) {
        const int na = s_na[r];
        if (na == 0) continue;
        const int x0 = s_xlo[r], x1 = s_xhi[r];
        const float* row = ybase + (size_t)(y0 + r) * HW;
        for (int px = x0 + tid; px <= x1; px += 256) {
            const float fx = (float)px;
            float lab = 0.0f;
            bool  valid = false;
            for (int k = 0; k < na; ++k) {
                float dx = fx - s_xc[r][k];
                if (dx * dx < s_lim[r][k]) { lab = s_lab[r][k]; valid = true; }
            }
            if (valid) {
                float l   = row[px];
                float bce = fmaxf(l, 0.0f) - l * lab + log1pf(expf(-fabsf(l)));
                sum += bce;
                cnt += 1.0f;
            }
        }
    }

    // wave shuffle reduce, then combine 4 waves via LDS
    for (int off = 32; off > 0; off >>= 1) {
        sum += __shfl_down(sum, off, 64);
        cnt += __shfl_down(cnt, off, 64);
    }
    __shared__ float rs[4], rc[4];
    if ((tid & 63) == 0) { rs[tid >> 6] = sum; rc[tid >> 6] = cnt; }
    __syncthreads();
    if (tid == 0) {
        float S = rs[0] + rs[1] + rs[2] + rs[3];
        float C = rc[0] + rc[1] + rc[2] + rc[3];
        ws[blockIdx.x * 2 + 0] = S;
        ws[blockIdx.x * 2 + 1] = C;
    }
}

// single-wave finalize: 256 float4 = 1024 floats, shuffle-only reduction
__global__ __launch_bounds__(64)
void pce_final_kernel(const float* __restrict__ ws, float* __restrict__ out) {
    const int tid = threadIdx.x;
    const float4* w4 = (const float4*)ws;   // {S,C,S,C} per float4
    float S = 0.0f, C = 0.0f;
    #pragma unroll
    for (int i = 0; i < 4; ++i) {
        float4 v = w4[tid + i * 64];
        S += v.x + v.z;
        C += v.y + v.w;
    }
    for (int off = 32; off > 0; off >>= 1) {
        S += __shfl_down(S, off, 64);
        C += __shfl_down(C, off, 64);
    }
    if (tid == 0) out[0] = (C > 0.0f) ? (S / C) : 0.0f;
}

extern "C" void kernel_launch(void* const* d_in, const int* in_sizes, int n_in,
                              void* d_out, int out_size, void* d_ws, size_t ws_size,
                              hipStream_t stream) {
    const float* y_pred       = (const float*)d_in[0];   // (8,1,512,512) f32
    const int*   point_labels = (const int*)d_in[1];     // (8,20) i32
    const float* point_coords = (const float*)d_in[2];   // (8,20,2) f32
    float*       out          = (float*)d_out;           // scalar f32
    float*       ws           = (float*)d_ws;            // 1024 floats, fully overwritten

    pce_main_kernel<<<NBLOCKS, 256, 0, stream>>>(y_pred, point_labels, point_coords, ws);
    pce_final_kernel<<<1, 64, 0, stream>>>(ws, out);
}